// Round 6
// baseline (132.800 us; speedup 1.0000x reference)
//
#include <hip/hip_runtime.h>

// B=4096, F0=39, D=16, L=(128,128), H1=64
// Round-20: 8-wave blocks (1 batch-pair/wave, wn-split, full K) + block-rotated
// L1 chunk order.  Floor recompute: mfma_32x32x16 = 32 cyc/SIMD (2495 TF), so
// floor = 23.7us and r16's 57us = 41% duty = measured MfmaUtil 44 -- counters
// consistent at full clock.  Per-wave cadence ~1250cyc = ~1 contended-L2 latency
// per chunk; 2 waves/SIMD can't hide it (r14's 4-wave null had 2x VALU/wave).
// This round: (a) 4 waves/SIMD, (b) halved per-wave VALU (8 pk_mul + 4 MFMA/chunk),
// (c) rot=blockIdx&15 rotates L1 group order so 512 blocks stop hammering the
// same L2 lines in lockstep (storm de-sync).  Reg ring dist-2 (LDS ring was null).
//  - mfma_f32_32x32x16_f16, M=32 = 2 batches x 16 d, N=128, K=(i,j) folded:
//    L0 upper-tri 30 chunks + L1 80 = 110.  Wave (w=0..7): wp=w>>1 (pair), wn=w&1.
// Layouts (verified): A: lane A[m=lane&31][k=(lane>>5)*8+t]; B: B[k=(lane>>5)*8+t][n=lane&31];
//  D: D[row=(r&3)+8*(r>>2)+4*(lane>>5)][col=lane&31]
// Repacked B (BYTES): ch*8192 + kh*4096 + cg*1024 + lane*16
//  L0 ch=0..29 (IG0/JG0): i=ig*4+kh*2+half, j=jg*8+t; folded (W'[i,j]=W[i,j]+W[j,i], j>i).
//  L1 ch=30+jg*5+ig: j=jg*4+kh*2+half, i=ig*8+t, zero-pad i>=39.  Total 901,120 B.

typedef _Float16 h2    __attribute__((ext_vector_type(2)));
typedef _Float16 f16x8 __attribute__((ext_vector_type(8)));
typedef __attribute__((ext_vector_type(16))) float f32x16;

#define XBB 1160   // per-batch halfs in xsH: 16 rows * 72 + 8 skew (2320 B, 16-aligned)
#define L0C 30
#define NCH 110

__device__ __constant__ int IG0[L0C] = {0,0,0,0,0, 1,1,1,1,1, 2,2,2,2, 3,3,3,3, 4,4,4, 5,5,5, 6,6, 7,7, 8, 9};
__device__ __constant__ int JG0[L0C] = {0,1,2,3,4, 0,1,2,3,4, 1,2,3,4, 1,2,3,4, 2,3,4, 2,3,4, 3,4, 3,4, 4, 4};
#define IG0T(c) ((c)<5?0:(c)<10?1:(c)<14?2:(c)<18?3:(c)<21?4:(c)<24?5:(c)<26?6:(c)<28?7:(c)<29?8:9)
#define JG0T(c) ((c)<10?((c)%5):(c)<18?(((c)-10)%4+1):(c)<24?(((c)-18)%3+2):(c)<28?(((c)-24)%2+3):4)

// ---------------- weight repack (unchanged layout) ----------------
__global__ __launch_bounds__(256)
void CIN_repack(const float* __restrict__ f0, const float* __restrict__ f1,
                uint4* __restrict__ ws)
{
    const int tid  = blockIdx.x * 256 + threadIdx.x;   // 56320 total
    const int n    = tid & 127;
    const int slot = tid >> 7;
    const int half = slot & 1;
    const int kh   = (slot >> 1) & 1;
    const int ch   = slot >> 2;                         // 0..109
    float v[8];
    if (ch < L0C) {
        const int ig = IG0[ch], jg = JG0[ch];
        const int i = ig * 4 + kh * 2 + half;
#pragma unroll
        for (int t = 0; t < 8; ++t) {
            const int j = jg * 8 + t;
            float val = 0.f;
            if (i < 39 && j < 39 && j >= i) {
                val = f0[(i * 39 + j) * 128 + n];
                if (j > i) val += f0[(j * 39 + i) * 128 + n];
            }
            v[t] = val;
        }
    } else {
        const int c1 = ch - L0C;
        const int jg = c1 / 5, ig = c1 - jg * 5;
        const int j = jg * 4 + kh * 2 + half;
#pragma unroll
        for (int t = 0; t < 8; ++t) {
            const int i = ig * 8 + t;
            v[t] = (i < 39) ? f1[(i * 64 + j) * 128 + n] : 0.f;
        }
    }
    union { h2 h[4]; uint4 q; } pk;
#pragma unroll
    for (int t = 0; t < 4; ++t)
        pk.h[t] = h2{(_Float16)v[2 * t], (_Float16)v[2 * t + 1]};
    const int lane = half * 32 + (n & 31);
    const int cg   = n >> 5;
    ws[ch * 512 + kh * 256 + cg * 64 + lane] = pk.q;
}

// ---- main: grid 512 x 512 threads, 8 batches/block, wave = 1 pair x wn-half,
// ---- full K per wave, reg ring dist-2, L1 order rotated by blockIdx&15 ----
__global__ __launch_bounds__(512, 4)
void CIN_main(const float* __restrict__ x,
              const char* __restrict__ wsB,
              const float* __restrict__ dw,
              const float* __restrict__ db,
              float* __restrict__ out)
{
    __shared__ __align__(16) _Float16 xsH[8 * XBB];    // [bb]: 16 rows of 72 (i<=39 used)
    __shared__ __align__(4)  _Float16 hsH[8][64][18];  // [bb][j][d]
    __shared__ float dws[192];
    __shared__ float red[8][2];

    const int tid  = threadIdx.x;
    const int w    = tid >> 6;     // 0..7
    const int wp   = w >> 1;       // batch-pair 0..3
    const int wn   = w & 1;        // n-half: quarters {2wn, 2wn+1}
    const int lane = tid & 63;
    const int half = lane >> 5;
    const int d    = lane & 15;
    const int bsel = (lane >> 4) & 1;
    const int col  = lane & 31;
    const int rot  = blockIdx.x & 15;   // L1 group rotation (storm de-sync)

    // B frag base; rebase +2560 so {kh*4096 + nq*1024} offsets fit imm13
    const char* wbase = wsB + lane * 16 + wn * 2048 + 2560;
    f16x8 Bb[2][2][2];             // [phase][kh][nq]
    auto loadBg = [&](int ch, f16x8 (&B)[2][2]) {
        const char* p0 = wbase + (size_t)ch * 8192;
        B[0][0] = *(const f16x8*)(p0 - 2560);
        B[0][1] = *(const f16x8*)(p0 - 1536);
        B[1][0] = *(const f16x8*)(p0 + 1536);
        B[1][1] = *(const f16x8*)(p0 + 2560);
    };

    loadBg(0, Bb[0]);              // distance-2 pipeline primed before x staging
    loadBg(1, Bb[1]);

    // ---- stage x for 8 batches as f16 (1248 float4, coalesced, 512 threads) ----
    const float4* xg4 = (const float4*)(x + (size_t)blockIdx.x * 8 * 624);
    for (int e4 = tid; e4 < 1248; e4 += 512) {
        float4 v = xg4[e4];
        int bb = e4 / 156, r = e4 - bb * 156;
        int i = r >> 2, d0 = (r & 3) * 4;
        _Float16* bp = xsH + bb * XBB + i;
        bp[(d0 + 0) * 72] = (_Float16)v.x; bp[(d0 + 1) * 72] = (_Float16)v.y;
        bp[(d0 + 2) * 72] = (_Float16)v.z; bp[(d0 + 3) * 72] = (_Float16)v.w;
    }
    if (tid < 128) { int bb = tid >> 4, dd = tid & 15; xsH[bb * XBB + dd * 72 + 39] = (_Float16)0.f; }
    if (tid < 192) dws[tid] = dw[tid];
    __syncthreads();

    // ---- xw: the 40 halfs of x[0..39] for THIS wave's pair, in registers ----
    const _Float16* xrow = xsH + (wp * 2 + bsel) * XBB + d * 72;
    h2 xw[20];
#pragma unroll
    for (int w5 = 0; w5 < 5; ++w5) {
        union { f16x8 v; h2 h[4]; } u;
        u.v = *(const f16x8*)(xrow + w5 * 8);    // one ds_read_b128
#pragma unroll
        for (int q = 0; q < 4; ++q) xw[w5 * 4 + q] = u.h[q];
    }

    f32x16 acc[2];                 // [nq]
#pragma unroll
    for (int nq = 0; nq < 2; ++nq)
#pragma unroll
        for (int r = 0; r < 16; ++r) acc[nq][r] = 0.f;

    h2 sp2[2];                     // [kh]

    // ---------------- layer 0: 30 chunks, fully unrolled, phase = c&1 ------
#pragma unroll
    for (int c = 0; c < L0C; ++c) {
        const int ig = IG0T(c);
        const int jg = JG0T(c);
        if ((c == 0) || (IG0T(c) != IG0T(c - 1))) {
            // xi: i = ig*4 + kh*2 + half -> reg xw[ig*2+kh], element = half
#pragma unroll
            for (int kh = 0; kh < 2; ++kh) {
                const h2 pr = xw[ig * 2 + kh];
                const _Float16 vv = half ? pr.y : pr.x;
                sp2[kh] = h2{vv, vv};
            }
        }
        union { h2 h[4]; f16x8 v; } a0, a1;
#pragma unroll
        for (int q = 0; q < 4; ++q) {
            a0.h[q] = sp2[0] * xw[jg * 4 + q];   // v_pk_mul_f16
            a1.h[q] = sp2[1] * xw[jg * 4 + q];
        }
        acc[0] = __builtin_amdgcn_mfma_f32_32x32x16_f16(a0.v, Bb[c & 1][0][0], acc[0], 0, 0, 0);
        acc[1] = __builtin_amdgcn_mfma_f32_32x32x16_f16(a0.v, Bb[c & 1][0][1], acc[1], 0, 0, 0);
        acc[0] = __builtin_amdgcn_mfma_f32_32x32x16_f16(a1.v, Bb[c & 1][1][0], acc[0], 0, 0, 0);
        acc[1] = __builtin_amdgcn_mfma_f32_32x32x16_f16(a1.v, Bb[c & 1][1][1], acc[1], 0, 0, 0);
        // prefetch c+2; c=28,29 feed the ROTATED start of L1
        const int lc = (c < 28) ? (c + 2) : (30 + rot * 5 + (c - 28));
        loadBg(lc, Bb[c & 1]);
    }

    // ---------------- layer-0 epilogue ----------------
    float cs[2] = {0.f, 0.f};
    if (wn == 0) {
        // n 0..63 -> h
#pragma unroll
        for (int nq = 0; nq < 2; ++nq)
#pragma unroll
            for (int r = 0; r < 16; r += 2) {
                const int row = (r & 3) + 8 * (r >> 2) + 4 * half;
                h2 pr = h2{(_Float16)fmaxf(acc[nq][r],     0.f),
                           (_Float16)fmaxf(acc[nq][r + 1], 0.f)};
                *(h2*)&hsH[wp * 2 + (row >> 4)][nq * 32 + col][row & 15] = pr;
            }
    } else {
        // n 64..127 -> finals, dot dw rows (n-64)
#pragma unroll
        for (int nq = 0; nq < 2; ++nq) {
            const float dwv = dws[nq * 32 + col];
#pragma unroll
            for (int r = 0; r < 16; ++r) {
                const int row = (r & 3) + 8 * (r >> 2) + 4 * half;
                cs[row >> 4] += fmaxf(acc[nq][r], 0.f) * dwv;
            }
        }
    }
#pragma unroll
    for (int nq = 0; nq < 2; ++nq)
#pragma unroll
        for (int r = 0; r < 16; ++r) acc[nq][r] = 0.f;
    __syncthreads();   // h visible to all waves

    // -------- layer 1: 4 outer x 20 unrolled, group g = (o2*4+u/5+rot)&15 ------
#pragma unroll 1
    for (int o2 = 0; o2 < 4; ++o2) {
#pragma unroll
        for (int u = 0; u < 20; ++u) {
            const int ig2 = u % 5;                 // position in group, compile-time
            const int g   = (o2 * 4 + u / 5 + rot) & 15;
            if (ig2 == 0) {
                const int jb = g * 4;
#pragma unroll
                for (int kh = 0; kh < 2; ++kh) {
                    const _Float16 s = hsH[wp * 2 + bsel][jb + kh * 2 + half][d];
                    sp2[kh] = h2{s, s};
                }
            }
            union { h2 h[4]; f16x8 v; } a0, a1;
#pragma unroll
            for (int q = 0; q < 4; ++q) {
                a0.h[q] = sp2[0] * xw[ig2 * 4 + q];
                a1.h[q] = sp2[1] * xw[ig2 * 4 + q];
            }
            acc[0] = __builtin_amdgcn_mfma_f32_32x32x16_f16(a0.v, Bb[u & 1][0][0], acc[0], 0, 0, 0);
            acc[1] = __builtin_amdgcn_mfma_f32_32x32x16_f16(a0.v, Bb[u & 1][0][1], acc[1], 0, 0, 0);
            acc[0] = __builtin_amdgcn_mfma_f32_32x32x16_f16(a1.v, Bb[u & 1][1][0], acc[0], 0, 0, 0);
            acc[1] = __builtin_amdgcn_mfma_f32_32x32x16_f16(a1.v, Bb[u & 1][1][1], acc[1], 0, 0, 0);
            // prefetch seq+2 in ROTATED order ((u+2)/5, (u+2)%5 compile-time;
            // o2=3,u>=18 wraps to group rot -- dead loads, harmless)
            const int g2  = (o2 * 4 + (u + 2) / 5 + rot) & 15;
            const int chn = 30 + g2 * 5 + (u + 2) % 5;
            loadBg(chn, Bb[u & 1]);
        }
    }

    // ---------------- layer-1 epilogue + reduction ----------------
#pragma unroll
    for (int nq = 0; nq < 2; ++nq) {
        const float dwv = dws[64 + (wn * 2 + nq) * 32 + col];
#pragma unroll
        for (int r = 0; r < 16; ++r) {
            const int row = (r & 3) + 8 * (r >> 2) + 4 * half;
            cs[row >> 4] += fmaxf(acc[nq][r], 0.f) * dwv;
        }
    }
#pragma unroll
    for (int rr = 0; rr < 2; ++rr)
#pragma unroll
        for (int off = 32; off > 0; off >>= 1)
            cs[rr] += __shfl_xor(cs[rr], off, 64);
    if (lane == 0) {
        red[w][0] = cs[0];
        red[w][1] = cs[1];
    }
    __syncthreads();
    // block batch bb = wp*2 + l; sum the two wn-halves
    if (tid < 8) {
        const int wpp = tid >> 1, l = tid & 1;
        out[blockIdx.x * 8 + tid] = red[wpp * 2][l] + red[wpp * 2 + 1][l] + db[0];
    }
}

extern "C" void kernel_launch(void* const* d_in, const int* in_sizes, int n_in,
                              void* d_out, int out_size, void* d_ws, size_t ws_size,
                              hipStream_t stream)
{
    const float* x  = (const float*)d_in[0];
    const float* f0 = (const float*)d_in[1];
    const float* f1 = (const float*)d_in[2];
    const float* dw = (const float*)d_in[3];
    const float* db = (const float*)d_in[4];
    float* out = (float*)d_out;

    CIN_repack<<<dim3(220), dim3(256), 0, stream>>>(f0, f1, (uint4*)d_ws);
    CIN_main<<<dim3(512), dim3(512), 0, stream>>>(x, (const char*)d_ws, dw, db, out);
}

// Round 7
// 118.405 us; speedup vs baseline: 1.1216x; 1.1216x over previous
//
#include <hip/hip_runtime.h>

// B=4096, F0=39, D=16, L=(128,128), H1=64
// Round-21: TRUE distance-4 LDS pipeline.  r16 (reg dist-2) and r18 (LDS ring,
// explicit vmcnt dist-2) both equilibrate at cadence ~1250 cyc/chunk ==
// latency/distance with contended B-latency ~2500 cyc (500 waves/XCD queued on
// the same 8KB chunk).  r20 killed TLP/de-sync theories.  This round: 5-buffer
// LDS ring (buf = s%5 -- compile-time everywhere since 30==0 mod 5), stage
// S(c+4) during chunk c, vmcnt(6) at chunk top (8 outstanding, drain to 6 =
// S(c) landed).  Equilibrium cadence -> 2500/4 ~= 625 cyc.  Also: acc split by
// kh (acc[kh][nq], 4 MFMA chains, dep-gap 128 cyc) -- removes any MFMA
// dependent-latency component; kh-partials summed before ReLU (exact).
//  - mfma_f32_32x32x16_f16, M=32 = 2 batches x 16 d, N=128, K=(i,j) folded:
//    L0 upper-tri 30 chunks + L1 80 = 110.  Wave = 2 batch-pairs x 2 n-quarters.
// Layouts (verified): A: lane A[m=lane&31][k=(lane>>5)*8+t]; B: B[k=(lane>>5)*8+t][n=lane&31];
//  D: D[row=(r&3)+8*(r>>2)+4*(lane>>5)][col=lane&31]
// Repacked B (BYTES): ch*8192 + kh*4096 + cg*1024 + lane*16
//  L0 ch=0..29 (IG0/JG0): i=ig*4+kh*2+half, j=jg*8+t; folded (W'[i,j]=W[i,j]+W[j,i], j>i).
//  L1 ch=30+jg*5+ig: j=jg*4+kh*2+half, i=ig*8+t, zero-pad i>=39.  Total 901,120 B.
// Per-chunk schedule: vmcnt(6) [S(c) landed] -> s_barrier -> ds_read frags(c)
//   -> stage S(c+4) -> build A -> 8 MFMA into 4 acc chains.  Stage clamps
//   data-chunk to 109 (dead writes land in never-again-read buffers).

typedef _Float16 h2    __attribute__((ext_vector_type(2)));
typedef _Float16 f16x8 __attribute__((ext_vector_type(8)));
typedef __attribute__((ext_vector_type(16))) float f32x16;

#define XBB 1160   // per-batch halfs in xsH: 16 rows * 72 + 8 skew (2320 B, 16-aligned)
#define L0C 30
#define NCH 110

__device__ __constant__ int IG0[L0C] = {0,0,0,0,0, 1,1,1,1,1, 2,2,2,2, 3,3,3,3, 4,4,4, 5,5,5, 6,6, 7,7, 8, 9};
__device__ __constant__ int JG0[L0C] = {0,1,2,3,4, 0,1,2,3,4, 1,2,3,4, 1,2,3,4, 2,3,4, 2,3,4, 3,4, 3,4, 4, 4};
#define IG0T(c) ((c)<5?0:(c)<10?1:(c)<14?2:(c)<18?3:(c)<21?4:(c)<24?5:(c)<26?6:(c)<28?7:(c)<29?8:9)
#define JG0T(c) ((c)<10?((c)%5):(c)<18?(((c)-10)%4+1):(c)<24?(((c)-18)%3+2):(c)<28?(((c)-24)%2+3):4)

// ---------------- weight repack (unchanged layout) ----------------
__global__ __launch_bounds__(256)
void CIN_repack(const float* __restrict__ f0, const float* __restrict__ f1,
                uint4* __restrict__ ws)
{
    const int tid  = blockIdx.x * 256 + threadIdx.x;   // 56320 total
    const int n    = tid & 127;
    const int slot = tid >> 7;
    const int half = slot & 1;
    const int kh   = (slot >> 1) & 1;
    const int ch   = slot >> 2;                         // 0..109
    float v[8];
    if (ch < L0C) {
        const int ig = IG0[ch], jg = JG0[ch];
        const int i = ig * 4 + kh * 2 + half;
#pragma unroll
        for (int t = 0; t < 8; ++t) {
            const int j = jg * 8 + t;
            float val = 0.f;
            if (i < 39 && j < 39 && j >= i) {
                val = f0[(i * 39 + j) * 128 + n];
                if (j > i) val += f0[(j * 39 + i) * 128 + n];
            }
            v[t] = val;
        }
    } else {
        const int c1 = ch - L0C;
        const int jg = c1 / 5, ig = c1 - jg * 5;
        const int j = jg * 4 + kh * 2 + half;
#pragma unroll
        for (int t = 0; t < 8; ++t) {
            const int i = ig * 8 + t;
            v[t] = (i < 39) ? f1[(i * 64 + j) * 128 + n] : 0.f;
        }
    }
    union { h2 h[4]; uint4 q; } pk;
#pragma unroll
    for (int t = 0; t < 4; ++t)
        pk.h[t] = h2{(_Float16)v[2 * t], (_Float16)v[2 * t + 1]};
    const int lane = half * 32 + (n & 31);
    const int cg   = n >> 5;
    ws[ch * 512 + kh * 256 + cg * 64 + lane] = pk.q;
}

// ---- main: grid 512, 8 batches/block, wave = 2 pairs x 2 n-quarters,
// ---- 5-buffer LDS ring, stage distance 4, vmcnt(6) ----
__global__ __launch_bounds__(256, 2)
void CIN_main(const float* __restrict__ x,
              const char* __restrict__ wsB,
              const float* __restrict__ dw,
              const float* __restrict__ db,
              float* __restrict__ out)
{
    __shared__ __align__(16) char bBc[5 * 8192];       // B chunk ring (40 KB)
    __shared__ __align__(16) _Float16 xsH[8 * XBB];    // [bb]: 16 rows of 72 (i<=39 used)
    __shared__ __align__(4)  _Float16 hsH[8][64][18];  // [bb][j][d]
    __shared__ float dws[192];
    __shared__ float red[4][4];

    const int tid  = threadIdx.x;
    const int w    = tid >> 6;
    const int wp   = w >> 1;       // batch-pair group: pairs {2wp, 2wp+1}
    const int wn   = w & 1;        // n-half: quarters {2wn, 2wn+1}
    const int lane = tid & 63;
    const int half = lane >> 5;
    const int d    = lane & 15;
    const int bsel = (lane >> 4) & 1;
    const int col  = lane & 31;

    // stage one 8KB chunk cooperatively: wave w covers bytes [w*2KB, w*2KB+2KB)
    auto stageB = [&](int ch, int buf) {
        const char* src = wsB + (size_t)ch * 8192 + w * 2048 + lane * 16;
        char* dst = bBc + buf * 8192 + w * 2048;
        __builtin_amdgcn_global_load_lds(
            (const __attribute__((address_space(1))) void*)(src),
            (__attribute__((address_space(3))) void*)(dst), 16, 0, 0);
        __builtin_amdgcn_global_load_lds(
            (const __attribute__((address_space(1))) void*)(src + 1024),
            (__attribute__((address_space(3))) void*)(dst + 1024), 16, 0, 0);
    };

    stageB(0, 0);                  // prime 4 chunks (drained by x-staging syncthreads)
    stageB(1, 1);
    stageB(2, 2);
    stageB(3, 3);

    // ---- stage x for 8 batches as f16 (1248 float4, coalesced) ----
    const float4* xg4 = (const float4*)(x + (size_t)blockIdx.x * 8 * 624);
    for (int e4 = tid; e4 < 1248; e4 += 256) {
        float4 v = xg4[e4];
        int bb = e4 / 156, r = e4 - bb * 156;
        int i = r >> 2, d0 = (r & 3) * 4;
        _Float16* bp = xsH + bb * XBB + i;
        bp[(d0 + 0) * 72] = (_Float16)v.x; bp[(d0 + 1) * 72] = (_Float16)v.y;
        bp[(d0 + 2) * 72] = (_Float16)v.z; bp[(d0 + 3) * 72] = (_Float16)v.w;
    }
    if (tid < 128) { int bb = tid >> 4, dd = tid & 15; xsH[bb * XBB + dd * 72 + 39] = (_Float16)0.f; }
    if (tid < 192) dws[tid] = dw[tid];
    __syncthreads();

    const _Float16* xrow[2] = {
        xsH + ((wp * 2 + 0) * 2 + bsel) * XBB + d * 72,
        xsH + ((wp * 2 + 1) * 2 + bsel) * XBB + d * 72
    };

    // ---- xw: the 40 halfs of x[0..39] per lane-pair, REGISTERS, serve both layers ----
    h2 xw[2][20];
#pragma unroll
    for (int p = 0; p < 2; ++p)
#pragma unroll
        for (int w5 = 0; w5 < 5; ++w5) {
            union { f16x8 v; h2 h[4]; } u;
            u.v = *(const f16x8*)(xrow[p] + w5 * 8);    // one ds_read_b128
#pragma unroll
            for (int q = 0; q < 4; ++q) xw[p][w5 * 4 + q] = u.h[q];
        }

    f32x16 acc[2][2][2];           // [kh][p][nq] -- 4 independent chains per p
#pragma unroll
    for (int kh = 0; kh < 2; ++kh)
#pragma unroll
        for (int p = 0; p < 2; ++p)
#pragma unroll
            for (int nq = 0; nq < 2; ++nq)
#pragma unroll
                for (int r = 0; r < 16; ++r) acc[kh][p][nq][r] = 0.f;

    h2 sp2[2][2];
    const char* bfr = bBc + wn * 2048 + (size_t)lane * 16;   // frag base (+buf*8192 per chunk)

    // ---------------- layer 0: 30 chunks, 5-ring, dist-4, vmcnt(6) ------
#pragma unroll
    for (int c = 0; c < L0C; ++c) {
        asm volatile("s_waitcnt vmcnt(6)" ::: "memory");   // S(c) landed in LDS
        __builtin_amdgcn_sched_barrier(0);
        __builtin_amdgcn_s_barrier();                      // everyone's S(c) landed
        const int ig = IG0T(c);
        const int jg = JG0T(c);
        if ((c == 0) || (IG0T(c) != IG0T(c - 1))) {
#pragma unroll
            for (int p = 0; p < 2; ++p)
#pragma unroll
                for (int kh = 0; kh < 2; ++kh) {
                    const h2 pr = xw[p][ig * 2 + kh];
                    const _Float16 vv = half ? pr.y : pr.x;
                    sp2[p][kh] = h2{vv, vv};
                }
        }
        const char* bb = bfr + (c % 5) * 8192;
        const f16x8 B00 = *(const f16x8*)(bb);
        const f16x8 B01 = *(const f16x8*)(bb + 1024);
        const f16x8 B10 = *(const f16x8*)(bb + 4096);
        const f16x8 B11 = *(const f16x8*)(bb + 5120);
        stageB(c + 4, (c + 4) % 5);                        // c+4 <= 33 <= 109
#pragma unroll
        for (int p = 0; p < 2; ++p) {
            union { h2 h[4]; f16x8 v; } a0, a1;
#pragma unroll
            for (int q = 0; q < 4; ++q) {
                a0.h[q] = sp2[p][0] * xw[p][jg * 4 + q];   // v_pk_mul_f16
                a1.h[q] = sp2[p][1] * xw[p][jg * 4 + q];
            }
            acc[0][p][0] = __builtin_amdgcn_mfma_f32_32x32x16_f16(a0.v, B00, acc[0][p][0], 0, 0, 0);
            acc[0][p][1] = __builtin_amdgcn_mfma_f32_32x32x16_f16(a0.v, B01, acc[0][p][1], 0, 0, 0);
            acc[1][p][0] = __builtin_amdgcn_mfma_f32_32x32x16_f16(a1.v, B10, acc[1][p][0], 0, 0, 0);
            acc[1][p][1] = __builtin_amdgcn_mfma_f32_32x32x16_f16(a1.v, B11, acc[1][p][1], 0, 0, 0);
        }
    }

    // ---------------- layer-0 epilogue (sum kh partials, then ReLU) ----------------
    float cs[4] = {0.f, 0.f, 0.f, 0.f};
    if (wn == 0) {
        // n 0..63 -> h
#pragma unroll
        for (int p = 0; p < 2; ++p)
#pragma unroll
            for (int nq = 0; nq < 2; ++nq)
#pragma unroll
                for (int r = 0; r < 16; r += 2) {
                    const int row = (r & 3) + 8 * (r >> 2) + 4 * half;
                    h2 pr = h2{(_Float16)fmaxf(acc[0][p][nq][r]     + acc[1][p][nq][r],     0.f),
                               (_Float16)fmaxf(acc[0][p][nq][r + 1] + acc[1][p][nq][r + 1], 0.f)};
                    *(h2*)&hsH[(wp * 2 + p) * 2 + (row >> 4)][nq * 32 + col][row & 15] = pr;
                }
    } else {
        // n 64..127 -> finals, dot dw rows (n-64)
#pragma unroll
        for (int nq = 0; nq < 2; ++nq) {
            const float dwv = dws[nq * 32 + col];
#pragma unroll
            for (int p = 0; p < 2; ++p)
#pragma unroll
                for (int r = 0; r < 16; ++r) {
                    const int row = (r & 3) + 8 * (r >> 2) + 4 * half;
                    cs[p * 2 + (row >> 4)] += fmaxf(acc[0][p][nq][r] + acc[1][p][nq][r], 0.f) * dwv;
                }
        }
    }
#pragma unroll
    for (int kh = 0; kh < 2; ++kh)
#pragma unroll
        for (int p = 0; p < 2; ++p)
#pragma unroll
            for (int nq = 0; nq < 2; ++nq)
#pragma unroll
                for (int r = 0; r < 16; ++r) acc[kh][p][nq][r] = 0.f;
    __syncthreads();   // h visible; drains S(30..33) (they land before L1 reads)

    // -------- layer 1: 4 outer x 20 unrolled chunks; s = 30+o2*20+u, buf = u%5 ------
#pragma unroll 1
    for (int o2 = 0; o2 < 4; ++o2) {
#pragma unroll
        for (int u = 0; u < 20; ++u) {
            asm volatile("s_waitcnt vmcnt(6)" ::: "memory");
            __builtin_amdgcn_sched_barrier(0);
            __builtin_amdgcn_s_barrier();
            const int ig2 = u % 5;                 // window index, compile-time
            if (ig2 == 0) {
                const int jb = (o2 * 4 + u / 5) * 4;
#pragma unroll
                for (int p = 0; p < 2; ++p)
#pragma unroll
                    for (int kh = 0; kh < 2; ++kh) {
                        const _Float16 s = hsH[(wp * 2 + p) * 2 + bsel][jb + kh * 2 + half][d];
                        sp2[p][kh] = h2{s, s};
                    }
            }
            const char* bb = bfr + (u % 5) * 8192;           // (30+o2*20+u)%5 == u%5
            const f16x8 B00 = *(const f16x8*)(bb);
            const f16x8 B01 = *(const f16x8*)(bb + 1024);
            const f16x8 B10 = *(const f16x8*)(bb + 4096);
            const f16x8 B11 = *(const f16x8*)(bb + 5120);
            int sn = 30 + o2 * 20 + u + 4; if (sn > NCH - 1) sn = NCH - 1;  // clamp: dead stage
            stageB(sn, (u + 4) % 5);               // (s+4)%5 == (u+4)%5, compile-time
#pragma unroll
            for (int p = 0; p < 2; ++p) {
                union { h2 h[4]; f16x8 v; } a0, a1;
#pragma unroll
                for (int q = 0; q < 4; ++q) {
                    a0.h[q] = sp2[p][0] * xw[p][ig2 * 4 + q];
                    a1.h[q] = sp2[p][1] * xw[p][ig2 * 4 + q];
                }
                acc[0][p][0] = __builtin_amdgcn_mfma_f32_32x32x16_f16(a0.v, B00, acc[0][p][0], 0, 0, 0);
                acc[0][p][1] = __builtin_amdgcn_mfma_f32_32x32x16_f16(a0.v, B01, acc[0][p][1], 0, 0, 0);
                acc[1][p][0] = __builtin_amdgcn_mfma_f32_32x32x16_f16(a1.v, B10, acc[1][p][0], 0, 0, 0);
                acc[1][p][1] = __builtin_amdgcn_mfma_f32_32x32x16_f16(a1.v, B11, acc[1][p][1], 0, 0, 0);
            }
        }
    }

    // ---------------- layer-1 epilogue + reduction ----------------
#pragma unroll
    for (int nq = 0; nq < 2; ++nq) {
        const float dwv = dws[64 + (wn * 2 + nq) * 32 + col];
#pragma unroll
        for (int p = 0; p < 2; ++p)
#pragma unroll
            for (int r = 0; r < 16; ++r) {
                const int row = (r & 3) + 8 * (r >> 2) + 4 * half;
                cs[p * 2 + (row >> 4)] += fmaxf(acc[0][p][nq][r] + acc[1][p][nq][r], 0.f) * dwv;
            }
    }
#pragma unroll
    for (int rr = 0; rr < 4; ++rr)
#pragma unroll
        for (int off = 32; off > 0; off >>= 1)
            cs[rr] += __shfl_xor(cs[rr], off, 64);
    if (lane == 0) {
#pragma unroll
        for (int rr = 0; rr < 4; ++rr) red[w][rr] = cs[rr];
    }
    __syncthreads();
    // block batch bb = wp*4 + l (l = cs index); sum the two n-halves
    if (tid < 8) {
        const int wpp = tid >> 2, l = tid & 3;
        out[blockIdx.x * 8 + tid] = red[wpp * 2][l] + red[wpp * 2 + 1][l] + db[0];
    }
}

extern "C" void kernel_launch(void* const* d_in, const int* in_sizes, int n_in,
                              void* d_out, int out_size, void* d_ws, size_t ws_size,
                              hipStream_t stream)
{
    const float* x  = (const float*)d_in[0];
    const float* f0 = (const float*)d_in[1];
    const float* f1 = (const float*)d_in[2];
    const float* dw = (const float*)d_in[3];
    const float* db = (const float*)d_in[4];
    float* out = (float*)d_out;

    CIN_repack<<<dim3(220), dim3(256), 0, stream>>>(f0, f1, (uint4*)d_ws);
    CIN_main<<<dim3(512), dim3(256), 0, stream>>>(x, (const char*)d_ws, dw, db, out);
}